// Round 14
// baseline (420.775 us; speedup 1.0000x reference)
//
#include <hip/hip_runtime.h>
#include <stdint.h>

// B=1024, T=187, H=256, C=5. Fully-fused persistent 2-layer RNN + FC.
// Transposed recurrence: ht = h^T in LDS as [batch col][feature]; state is
// the MFMA B-operand, weights (A-operand f16 frags) register-resident.
// 64 blocks x 16 batch cols, 8 waves, 32-feature M-slice/wave.
//
// REGISTER MODEL (measured): 512 unified regs/SIMD; arch caps at half;
//   compiler never spills to idle AGPRs; "+a" pins work.
//   R16 (best, 308us): AGPR(pinned) = wi1 64 + wh1 64 = 128; arch =
//   wh0 64 + acc + B-frags + misc ~122 <= 128; bias/wi0 in LDS.
// SCHEDULE LOG: R17 wave phase-skew (waves 4-7 l1-first) = 335us REFUTED
//   (MfmaUtil down; dual-order code hurt). But R17 proved ah1+extra regs
//   held through l0_fin do NOT spill (WRITE_SIZE 3.6MB) -> slack exists.
// R18, three LDS/issue trims on the R16 base:
//   1. UNIFORM reorder l0_mfma -> l1_mfma -> l0_fin -> l1_fin: B1 reads
//      issue before l0's tanh -> B1 LDS latency hides under VALU. Never
//      tested (R17 only tested the skewed variant). Register-proven fit.
//   2. Bias tables f16-packed: (b0,wi0) interleaved -> 1 b128/mt (was 2);
//      b1 as f16x4 b64. 6 -> 4 bias reads/thread-step, narrower.
//   3. FC epilogue vectorized f16x8 (was 256 scalar ds_read_u16/thread).
// R19: broker timeout, R18 never ran. Resubmitted unchanged.
// PREDICT: dur 308 -> 275-290us; WRITE_SIZE ~4.6MB (gate: >7MB = spill,
//   revert reorder). KILL: dur >= 308 -> R16 keeper; intra-CU family done.
// (R13 lesson: full #pragma unroll always.)

#define Bsz 1024
#define Tt  187
#define Hh  256
#define Cc  5
#define ST  264      // f16 elems per batch-col row (256 + 8 pad)
#define XS  188      // x LDS stride (187 + 1)

typedef _Float16 f16x8 __attribute__((ext_vector_type(8)));
typedef _Float16 f16x4 __attribute__((ext_vector_type(4)));
typedef __fp16   fp16x2 __attribute__((ext_vector_type(2)));  // cvt_pkrtz native type
typedef float    f32x4 __attribute__((ext_vector_type(4)));

// Force a fragment into the AGPR half of the unified file (R11/R15/R16-proven).
#define PIN_AGPR(v) asm volatile("" : "+a"(v))

__device__ __forceinline__ float tanh_fast(float z) {
    float e = __expf(2.0f * z);
    return 1.0f - 2.0f * __builtin_amdgcn_rcpf(1.0f + e);
}

__device__ __forceinline__ unsigned pk2(float a, float b) {
    union { fp16x2 h; unsigned u; } v;
    v.h = __builtin_amdgcn_cvt_pkrtz(a, b);
    return v.u;
}

__global__ void __launch_bounds__(512, 2)
rnn_fused(const float* __restrict__ x,     // [B][T]
          const float* __restrict__ Wih0,  // [H][1]
          const float* __restrict__ Whh0,  // [H][H]
          const float* __restrict__ bih0,
          const float* __restrict__ bhh0,
          const float* __restrict__ Wih1,  // [H][H]
          const float* __restrict__ Whh1,  // [H][H]
          const float* __restrict__ bih1,
          const float* __restrict__ bhh1,
          const float* __restrict__ Wfc,   // [C][H]
          const float* __restrict__ bfc,   // [C]
          float* __restrict__ out)         // [B][C]
{
    __shared__ __align__(16) _Float16 ht0[2][16 * ST];
    __shared__ __align__(16) _Float16 ht1[2][16 * ST];
    __shared__ float xs[16 * XS];
    __shared__ __align__(16) _Float16 pkA[2 * Hh];  // interleaved {b0sum, wi0} f16 pairs
    __shared__ __align__(8)  _Float16 pkB[Hh];      // b1sum f16

    const int tid  = threadIdx.x;
    const int lane = tid & 63;
    const int w    = tid >> 6;     // wave 0..7 -> features [32w, 32w+32)
    const int q    = lane >> 4;
    const int c    = lane & 15;    // batch col within block
    const int bb   = blockIdx.x * 16;

    // ---- one-time: stage weight A-fragments (f16) ----
    // wi1, wh1 -> AGPR half (pinned, 128 exactly). wh0 -> arch VGPRs (64).
    f16x8 wh0[2][8], wi1[2][8], wh1[2][8];
#pragma unroll
    for (int mt = 0; mt < 2; ++mt) {
        const int fb = 32 * w + 16 * mt;
        const int m = fb + c;
#pragma unroll
        for (int kt = 0; kt < 8; ++kt) {
            const int off = m * Hh + kt * 32 + q * 8;
            {
                const float4 a0 = *(const float4*)(Whh0 + off);
                const float4 a1 = *(const float4*)(Whh0 + off + 4);
                wh0[mt][kt] = (f16x8){(_Float16)a0.x, (_Float16)a0.y, (_Float16)a0.z, (_Float16)a0.w,
                                      (_Float16)a1.x, (_Float16)a1.y, (_Float16)a1.z, (_Float16)a1.w};
            }
            {
                const float4 a0 = *(const float4*)(Wih1 + off);
                const float4 a1 = *(const float4*)(Wih1 + off + 4);
                wi1[mt][kt] = (f16x8){(_Float16)a0.x, (_Float16)a0.y, (_Float16)a0.z, (_Float16)a0.w,
                                      (_Float16)a1.x, (_Float16)a1.y, (_Float16)a1.z, (_Float16)a1.w};
                PIN_AGPR(wi1[mt][kt]);
            }
            {
                const float4 a0 = *(const float4*)(Whh1 + off);
                const float4 a1 = *(const float4*)(Whh1 + off + 4);
                wh1[mt][kt] = (f16x8){(_Float16)a0.x, (_Float16)a0.y, (_Float16)a0.z, (_Float16)a0.w,
                                      (_Float16)a1.x, (_Float16)a1.y, (_Float16)a1.z, (_Float16)a1.w};
                PIN_AGPR(wh1[mt][kt]);
            }
        }
    }

    // ---- init LDS: x tile, packed biases, ht1 = 0 (both), ht0[0] ----
    for (int i = tid; i < 16 * Tt; i += 512) {
        const int b = i / Tt, t = i - b * Tt;
        xs[b * XS + t] = x[(bb + b) * Tt + t];
    }
    if (tid < Hh) {
        pkA[2 * tid]     = (_Float16)(bih0[tid] + bhh0[tid]);
        pkA[2 * tid + 1] = (_Float16)(Wih0[tid]);
        pkB[tid]         = (_Float16)(bih1[tid] + bhh1[tid]);
    }
    {
        _Float16* z = &ht1[0][0];
        for (int i = tid; i < 2 * 16 * ST; i += 512) z[i] = (_Float16)0.f;
    }
    for (int i = tid; i < 16 * Hh; i += 512) {
        const int b = i >> 8, f = i & 255;
        const float xv0 = x[(bb + b) * Tt];
        ht0[0][b * ST + f] =
            (_Float16)tanh_fast(xv0 * Wih0[f] + bih0[f] + bhh0[f]);
    }
    __syncthreads();

    // B-operand read base: lane (q,c) reg j needs ht[k=kt*32+q*8+j][col c]
    const int rdoff = c * ST + q * 8;
    const int wroff = c * ST + 32 * w + 4 * q;   // D write: [c][fb+4q .. +3]
    const int fq    = 32 * w + 4 * q;            // bias base for mt=0 (+16 for mt=1)

    // ---- main recurrence, time-skewed:
    // step s: B0 = ht0[s]; produce ht0[s+1] (Whh0) and ht1[s] (Wih1 + Whh1)
#pragma unroll 1
    for (int s = 0; s < Tt; ++s) {
        const int cur = s & 1, nxt = cur ^ 1;
        const _Float16* B0p = &ht0[cur][rdoff];
        const _Float16* B1p = &ht1[nxt][rdoff];   // ht1[s-1]
        int sn = s + 1; if (sn >= Tt) sn = Tt - 1;  // last h0_next unused
        const float xv = xs[c * XS + sn];

        const f32x4 z4 = (f32x4){0.f, 0.f, 0.f, 0.f};

        // -- l0 MFMA: ai = Wih1 . ht0 ; ah0 = Whh0 . ht0 (shared B-frag)
        f32x4 ai[2]  = {z4, z4};
        f32x4 ah0[2] = {z4, z4};
#pragma unroll
        for (int kt = 0; kt < 8; ++kt) {
            const f16x8 B = *(const f16x8*)(B0p + kt * 32);
            ai[0]  = __builtin_amdgcn_mfma_f32_16x16x32_f16(wi1[0][kt], B, ai[0],  0, 0, 0);
            ai[1]  = __builtin_amdgcn_mfma_f32_16x16x32_f16(wi1[1][kt], B, ai[1],  0, 0, 0);
            ah0[0] = __builtin_amdgcn_mfma_f32_16x16x32_f16(wh0[0][kt], B, ah0[0], 0, 0, 0);
            ah0[1] = __builtin_amdgcn_mfma_f32_16x16x32_f16(wh0[1][kt], B, ah0[1], 0, 0, 0);
        }

        // -- l1 MFMA issued BEFORE l0 finish: B1 LDS latency hides under tanh
        f32x4 ah1[2] = {z4, z4};
#pragma unroll
        for (int kt = 0; kt < 8; ++kt) {
            const f16x8 B = *(const f16x8*)(B1p + kt * 32);
            ah1[0] = __builtin_amdgcn_mfma_f32_16x16x32_f16(wh1[0][kt], B, ah1[0], 0, 0, 0);
            ah1[1] = __builtin_amdgcn_mfma_f32_16x16x32_f16(wh1[1][kt], B, ah1[1], 0, 0, 0);
        }

        // -- l0 finish: ht0[s+1] = tanh(ah0 + b0 + x_{s+1}*wi0)
        // pkA read: one b128 per mt delivers {b0,w0} for 4 features.
#pragma unroll
        for (int mt = 0; mt < 2; ++mt) {
            const f16x8 bw = *(const f16x8*)&pkA[2 * (fq + 16 * mt)];
            const float t0 = tanh_fast(ah0[mt][0] + (float)bw[0] + xv * (float)bw[1]);
            const float t1 = tanh_fast(ah0[mt][1] + (float)bw[2] + xv * (float)bw[3]);
            const float t2 = tanh_fast(ah0[mt][2] + (float)bw[4] + xv * (float)bw[5]);
            const float t3 = tanh_fast(ah0[mt][3] + (float)bw[6] + xv * (float)bw[7]);
            *(uint2*)(&ht0[nxt][wroff + 16 * mt]) = make_uint2(pk2(t0, t1), pk2(t2, t3));
        }

        // -- l1 finish: ht1[s] = tanh(ai + ah1 + b1)
#pragma unroll
        for (int mt = 0; mt < 2; ++mt) {
            const f16x4 b1r = *(const f16x4*)&pkB[fq + 16 * mt];
            const float t0 = tanh_fast(ai[mt][0] + ah1[mt][0] + (float)b1r[0]);
            const float t1 = tanh_fast(ai[mt][1] + ah1[mt][1] + (float)b1r[1]);
            const float t2 = tanh_fast(ai[mt][2] + ah1[mt][2] + (float)b1r[2]);
            const float t3 = tanh_fast(ai[mt][3] + ah1[mt][3] + (float)b1r[3]);
            *(uint2*)(&ht1[cur][wroff + 16 * mt]) = make_uint2(pk2(t0, t1), pk2(t2, t3));
        }
        __syncthreads();   // double-buffered: one barrier per step
    }

    // ---- FC epilogue (vectorized): out = ht1_final . Wfc^T + bfc ----
    if (tid < 16 * Cc) {
        const int b = tid / Cc, cls = tid - Cc * (tid / Cc);
        const f16x8* hv = (const f16x8*)&ht1[(Tt - 1) & 1][b * ST];
        const float* wr = Wfc + cls * Hh;
        float acc = bfc[cls];
#pragma unroll 4
        for (int k8 = 0; k8 < Hh / 8; ++k8) {
            const f16x8 v = hv[k8];
#pragma unroll
            for (int j = 0; j < 8; ++j)
                acc += (float)v[j] * wr[k8 * 8 + j];
        }
        out[(bb + b) * Cc + cls] = acc;
    }
}

extern "C" void kernel_launch(void* const* d_in, const int* in_sizes, int n_in,
                              void* d_out, int out_size, void* d_ws, size_t ws_size,
                              hipStream_t stream) {
    rnn_fused<<<dim3(Bsz / 16), dim3(512), 0, stream>>>(
        (const float*)d_in[0],  // x
        (const float*)d_in[1],  // W_ih0
        (const float*)d_in[2],  // W_hh0
        (const float*)d_in[3],  // b_ih0
        (const float*)d_in[4],  // b_hh0
        (const float*)d_in[5],  // W_ih1
        (const float*)d_in[6],  // W_hh1
        (const float*)d_in[7],  // b_ih1
        (const float*)d_in[8],  // b_hh1
        (const float*)d_in[9],  // W_fc
        (const float*)d_in[10], // b_fc
        (float*)d_out);
}

// Round 15
// 393.777 us; speedup vs baseline: 1.0686x; 1.0686x over previous
//
#include <hip/hip_runtime.h>
#include <stdint.h>

// B=1024, T=187, H=256, C=5. Fully-fused persistent 2-layer RNN + FC.
// Transposed recurrence: ht = h^T in LDS as [batch col][feature]; state is
// the MFMA B-operand, weights (A-operand f16 frags) register-resident.
// 64 blocks x 16 batch cols, 8 waves, 32-feature M-slice/wave.
//
// REGISTER MODEL (measured): 512 unified regs/SIMD; arch caps at half;
//   compiler never spills to idle AGPRs; "+a" pins work.
//   R16 (best, 308us): AGPR(pinned) = wi1 64 + wh1 64 = 128; arch =
//   wh0 64 + acc + B-frags + misc ~122 <= 128; bias/wi0 in LDS.
// SCHEDULE LOG:
//   R17 wave phase-skew = 335us REFUTED.
//   R18 uniform reorder (ai+ah0+ah1 all live across both MFMA loops) =
//     362us, WRITE_SIZE 12.3MB -> spill gate fired. LESSON: every
//     accumulator set must DIE before the next is born; R16's phase
//     order is the only spill-free one.
// R19 (this round): R16 order + register-REDUCING algebra + safe trims:
//   1. CHAINED C-IN: layer1 recurrent MFMA accumulates directly into ai
//      (acc = mfma(wh1[kt], B1, acc), acc init = ai). Same f32 sum
//      (assoc order shifts; absmax 4.9e-4 vs 2.05e-3 = 4x headroom).
//      -8 arch regs peak, -8 VALU adds/step. Peak arch ~108 <= 128.
//   2. Bias tables f16-packed: (b0,wi0) interleaved -> 1 b128/mt; b1 b64.
//   3. FC epilogue vectorized f16x8.
// PREDICT: WRITE_SIZE <= 5MB; dur 290-305us; MfmaUtil ~10%.
// KILL: dur >= 308 -> R16 is final keeper (resubmit exact R16 next).
// (R13 lesson: full #pragma unroll always.)

#define Bsz 1024
#define Tt  187
#define Hh  256
#define Cc  5
#define ST  264      // f16 elems per batch-col row (256 + 8 pad)
#define XS  188      // x LDS stride (187 + 1)

typedef _Float16 f16x8 __attribute__((ext_vector_type(8)));
typedef _Float16 f16x4 __attribute__((ext_vector_type(4)));
typedef __fp16   fp16x2 __attribute__((ext_vector_type(2)));  // cvt_pkrtz native type
typedef float    f32x4 __attribute__((ext_vector_type(4)));

// Force a fragment into the AGPR half of the unified file (R11/R15/R16-proven).
#define PIN_AGPR(v) asm volatile("" : "+a"(v))

__device__ __forceinline__ float tanh_fast(float z) {
    float e = __expf(2.0f * z);
    return 1.0f - 2.0f * __builtin_amdgcn_rcpf(1.0f + e);
}

__device__ __forceinline__ unsigned pk2(float a, float b) {
    union { fp16x2 h; unsigned u; } v;
    v.h = __builtin_amdgcn_cvt_pkrtz(a, b);
    return v.u;
}

__global__ void __launch_bounds__(512, 2)
rnn_fused(const float* __restrict__ x,     // [B][T]
          const float* __restrict__ Wih0,  // [H][1]
          const float* __restrict__ Whh0,  // [H][H]
          const float* __restrict__ bih0,
          const float* __restrict__ bhh0,
          const float* __restrict__ Wih1,  // [H][H]
          const float* __restrict__ Whh1,  // [H][H]
          const float* __restrict__ bih1,
          const float* __restrict__ bhh1,
          const float* __restrict__ Wfc,   // [C][H]
          const float* __restrict__ bfc,   // [C]
          float* __restrict__ out)         // [B][C]
{
    __shared__ __align__(16) _Float16 ht0[2][16 * ST];
    __shared__ __align__(16) _Float16 ht1[2][16 * ST];
    __shared__ float xs[16 * XS];
    __shared__ __align__(16) _Float16 pkA[2 * Hh];  // interleaved {b0sum, wi0} f16 pairs
    __shared__ __align__(8)  _Float16 pkB[Hh];      // b1sum f16

    const int tid  = threadIdx.x;
    const int lane = tid & 63;
    const int w    = tid >> 6;     // wave 0..7 -> features [32w, 32w+32)
    const int q    = lane >> 4;
    const int c    = lane & 15;    // batch col within block
    const int bb   = blockIdx.x * 16;

    // ---- one-time: stage weight A-fragments (f16) ----
    // wi1, wh1 -> AGPR half (pinned, 128 exactly). wh0 -> arch VGPRs (64).
    f16x8 wh0[2][8], wi1[2][8], wh1[2][8];
#pragma unroll
    for (int mt = 0; mt < 2; ++mt) {
        const int fb = 32 * w + 16 * mt;
        const int m = fb + c;
#pragma unroll
        for (int kt = 0; kt < 8; ++kt) {
            const int off = m * Hh + kt * 32 + q * 8;
            {
                const float4 a0 = *(const float4*)(Whh0 + off);
                const float4 a1 = *(const float4*)(Whh0 + off + 4);
                wh0[mt][kt] = (f16x8){(_Float16)a0.x, (_Float16)a0.y, (_Float16)a0.z, (_Float16)a0.w,
                                      (_Float16)a1.x, (_Float16)a1.y, (_Float16)a1.z, (_Float16)a1.w};
            }
            {
                const float4 a0 = *(const float4*)(Wih1 + off);
                const float4 a1 = *(const float4*)(Wih1 + off + 4);
                wi1[mt][kt] = (f16x8){(_Float16)a0.x, (_Float16)a0.y, (_Float16)a0.z, (_Float16)a0.w,
                                      (_Float16)a1.x, (_Float16)a1.y, (_Float16)a1.z, (_Float16)a1.w};
                PIN_AGPR(wi1[mt][kt]);
            }
            {
                const float4 a0 = *(const float4*)(Whh1 + off);
                const float4 a1 = *(const float4*)(Whh1 + off + 4);
                wh1[mt][kt] = (f16x8){(_Float16)a0.x, (_Float16)a0.y, (_Float16)a0.z, (_Float16)a0.w,
                                      (_Float16)a1.x, (_Float16)a1.y, (_Float16)a1.z, (_Float16)a1.w};
                PIN_AGPR(wh1[mt][kt]);
            }
        }
    }

    // ---- init LDS: x tile, packed biases, ht1 = 0 (both), ht0[0] ----
    for (int i = tid; i < 16 * Tt; i += 512) {
        const int b = i / Tt, t = i - b * Tt;
        xs[b * XS + t] = x[(bb + b) * Tt + t];
    }
    if (tid < Hh) {
        pkA[2 * tid]     = (_Float16)(bih0[tid] + bhh0[tid]);
        pkA[2 * tid + 1] = (_Float16)(Wih0[tid]);
        pkB[tid]         = (_Float16)(bih1[tid] + bhh1[tid]);
    }
    {
        _Float16* z = &ht1[0][0];
        for (int i = tid; i < 2 * 16 * ST; i += 512) z[i] = (_Float16)0.f;
    }
    for (int i = tid; i < 16 * Hh; i += 512) {
        const int b = i >> 8, f = i & 255;
        const float xv0 = x[(bb + b) * Tt];
        ht0[0][b * ST + f] =
            (_Float16)tanh_fast(xv0 * Wih0[f] + bih0[f] + bhh0[f]);
    }
    __syncthreads();

    // B-operand read base: lane (q,c) reg j needs ht[k=kt*32+q*8+j][col c]
    const int rdoff = c * ST + q * 8;
    const int wroff = c * ST + 32 * w + 4 * q;   // D write: [c][fb+4q .. +3]
    const int fq    = 32 * w + 4 * q;            // bias base for mt=0 (+16 for mt=1)

    // ---- main recurrence, time-skewed (R16 phase order):
    // step s: B0 = ht0[s]; produce ht0[s+1] (Whh0) and ht1[s] (Wih1 + Whh1)
#pragma unroll 1
    for (int s = 0; s < Tt; ++s) {
        const int cur = s & 1, nxt = cur ^ 1;
        const _Float16* B0p = &ht0[cur][rdoff];
        const _Float16* B1p = &ht1[nxt][rdoff];   // ht1[s-1]
        int sn = s + 1; if (sn >= Tt) sn = Tt - 1;  // last h0_next unused
        const float xv = xs[c * XS + sn];

        const f32x4 z4 = (f32x4){0.f, 0.f, 0.f, 0.f};

        // -- l0 MFMA: ai = Wih1 . ht0 ; ah0 = Whh0 . ht0 (shared B-frag)
        f32x4 ai[2]  = {z4, z4};
        f32x4 ah0[2] = {z4, z4};
#pragma unroll
        for (int kt = 0; kt < 8; ++kt) {
            const f16x8 B = *(const f16x8*)(B0p + kt * 32);
            ai[0]  = __builtin_amdgcn_mfma_f32_16x16x32_f16(wi1[0][kt], B, ai[0],  0, 0, 0);
            ai[1]  = __builtin_amdgcn_mfma_f32_16x16x32_f16(wi1[1][kt], B, ai[1],  0, 0, 0);
            ah0[0] = __builtin_amdgcn_mfma_f32_16x16x32_f16(wh0[0][kt], B, ah0[0], 0, 0, 0);
            ah0[1] = __builtin_amdgcn_mfma_f32_16x16x32_f16(wh0[1][kt], B, ah0[1], 0, 0, 0);
        }

        // -- l0 finish: ht0[s+1] = tanh(ah0 + b0 + x_{s+1}*wi0); ah0 dies here
#pragma unroll
        for (int mt = 0; mt < 2; ++mt) {
            const f16x8 bw = *(const f16x8*)&pkA[2 * (fq + 16 * mt)];
            const float t0 = tanh_fast(ah0[mt][0] + (float)bw[0] + xv * (float)bw[1]);
            const float t1 = tanh_fast(ah0[mt][1] + (float)bw[2] + xv * (float)bw[3]);
            const float t2 = tanh_fast(ah0[mt][2] + (float)bw[4] + xv * (float)bw[5]);
            const float t3 = tanh_fast(ah0[mt][3] + (float)bw[6] + xv * (float)bw[7]);
            *(uint2*)(&ht0[nxt][wroff + 16 * mt]) = make_uint2(pk2(t0, t1), pk2(t2, t3));
        }

        // -- l1 MFMA, CHAINED C-IN: accumulate Whh1 . ht1[s-1] into ai
        // (no separate ah1 set; -8 arch regs peak, -8 VALU adds)
#pragma unroll
        for (int kt = 0; kt < 8; ++kt) {
            const f16x8 B = *(const f16x8*)(B1p + kt * 32);
            ai[0] = __builtin_amdgcn_mfma_f32_16x16x32_f16(wh1[0][kt], B, ai[0], 0, 0, 0);
            ai[1] = __builtin_amdgcn_mfma_f32_16x16x32_f16(wh1[1][kt], B, ai[1], 0, 0, 0);
        }

        // -- l1 finish: ht1[s] = tanh(ai + b1)
#pragma unroll
        for (int mt = 0; mt < 2; ++mt) {
            const f16x4 b1r = *(const f16x4*)&pkB[fq + 16 * mt];
            const float t0 = tanh_fast(ai[mt][0] + (float)b1r[0]);
            const float t1 = tanh_fast(ai[mt][1] + (float)b1r[1]);
            const float t2 = tanh_fast(ai[mt][2] + (float)b1r[2]);
            const float t3 = tanh_fast(ai[mt][3] + (float)b1r[3]);
            *(uint2*)(&ht1[cur][wroff + 16 * mt]) = make_uint2(pk2(t0, t1), pk2(t2, t3));
        }
        __syncthreads();   // double-buffered: one barrier per step
    }

    // ---- FC epilogue (vectorized): out = ht1_final . Wfc^T + bfc ----
    if (tid < 16 * Cc) {
        const int b = tid / Cc, cls = tid - Cc * (tid / Cc);
        const f16x8* hv = (const f16x8*)&ht1[(Tt - 1) & 1][b * ST];
        const float* wr = Wfc + cls * Hh;
        float acc = bfc[cls];
#pragma unroll 4
        for (int k8 = 0; k8 < Hh / 8; ++k8) {
            const f16x8 v = hv[k8];
#pragma unroll
            for (int j = 0; j < 8; ++j)
                acc += (float)v[j] * wr[k8 * 8 + j];
        }
        out[(bb + b) * Cc + cls] = acc;
    }
}

extern "C" void kernel_launch(void* const* d_in, const int* in_sizes, int n_in,
                              void* d_out, int out_size, void* d_ws, size_t ws_size,
                              hipStream_t stream) {
    rnn_fused<<<dim3(Bsz / 16), dim3(512), 0, stream>>>(
        (const float*)d_in[0],  // x
        (const float*)d_in[1],  // W_ih0
        (const float*)d_in[2],  // W_hh0
        (const float*)d_in[3],  // b_ih0
        (const float*)d_in[4],  // b_hh0
        (const float*)d_in[5],  // W_ih1
        (const float*)d_in[6],  // W_hh1
        (const float*)d_in[7],  // b_ih1
        (const float*)d_in[8],  // b_hh1
        (const float*)d_in[9],  // W_fc
        (const float*)d_in[10], // b_fc
        (float*)d_out);
}

// Round 18
// 368.330 us; speedup vs baseline: 1.1424x; 1.0691x over previous
//
#include <hip/hip_runtime.h>
#include <stdint.h>

// B=1024, T=187, H=256, C=5. Fully-fused persistent 2-layer RNN + FC.
// Transposed recurrence: ht = h^T in LDS as [batch col][feature]; state is
// the MFMA B-operand, weights (A-operand f16 frags) register-resident.
// 64 blocks x 16 batch cols, 8 waves, 32-feature M-slice/wave.
//
// REGISTER MODEL (measured): 512 unified regs/SIMD; arch caps at half;
//   compiler never spills to idle AGPRs; "+a" pins work.
//   R16 (best, 308us): AGPR(pinned) = wi1 64 + wh1 64 = 128; arch ~122.
// SCHEDULE LOG: R17 skew 335 / R18 reorder 362 (acc spill) / R19 chained
//   C-in 334 -- ALL REFUTED. R16 phase order + f32 biases = keeper.
// R20: LDS BANK-CONFLICT FIX (T2), single variable on the exact R16 base.
//   Bank analysis of the OLD padded layout (row stride 528B): row base
//   gives bank 4d, kt-stride 64B gives 16*(kt&1) -> for fixed kt ALL 64
//   lanes read in the SAME 16-bank half (16 words/bank, other half idle)
//   = structural ~2x B-read service penalty; matches the bit-identical
//   SQ_LDS_BANK_CONFLICT=7.85M across R8/R16/R17/R19.
//   Change: ST 264->256 (row 512B, bank-neutral base) + XOR swizzle
//   within-row byte ^= (c&7)<<4 on BOTH writes and reads (one involution
//   used on init-write, loop-write, loop-read, FC-read; 16B reads stay
//   contiguous, 8B stores aligned). Spreads reads 8 words/bank (even).
//   Folds: rbase = c*RB + 16*(q^(d&3)) + 64*(d>>2);
//   off(kt) = (rbase ^ ((kt&1)<<6)) + 128*(kt>>1); write = wbase^(mt<<5).
//   Algebra re-verified R22: write-path bit overlap (8q bit4 vs 16d) is
//   handled because per-bit XOR commutes; adds can't carry into swizzle
//   bits; 16B/8B alignment preserved.
// GATES: conflicts <2M (mechanism). H1 -> dur 265-285us; H2 -> ~308.
//   dur<305 keep; dur>=308 + conflicts collapsed -> R16 final.
//   WRITE>7MB -> reg overflow, revert.
// R21/R22 notes: container-failed-twice, then broker timeout; resubmitted.

#define Bsz 1024
#define Tt  187
#define Hh  256
#define Cc  5
#define RB  512      // bytes per batch-col row (256 f16, NO pad; swizzled)
#define XS  188      // x LDS stride (187 + 1)

typedef _Float16 f16x8 __attribute__((ext_vector_type(8)));
typedef __fp16   fp16x2 __attribute__((ext_vector_type(2)));  // cvt_pkrtz native type
typedef float    f32x4 __attribute__((ext_vector_type(4)));

// Force a fragment into the AGPR half of the unified file (R11/R15/R16-proven).
#define PIN_AGPR(v) asm volatile("" : "+a"(v))

__device__ __forceinline__ float tanh_fast(float z) {
    float e = __expf(2.0f * z);
    return 1.0f - 2.0f * __builtin_amdgcn_rcpf(1.0f + e);
}

__device__ __forceinline__ unsigned pk2(float a, float b) {
    union { fp16x2 h; unsigned u; } v;
    v.h = __builtin_amdgcn_cvt_pkrtz(a, b);
    return v.u;
}

__global__ void __launch_bounds__(512, 2)
rnn_fused(const float* __restrict__ x,     // [B][T]
          const float* __restrict__ Wih0,  // [H][1]
          const float* __restrict__ Whh0,  // [H][H]
          const float* __restrict__ bih0,
          const float* __restrict__ bhh0,
          const float* __restrict__ Wih1,  // [H][H]
          const float* __restrict__ Whh1,  // [H][H]
          const float* __restrict__ bih1,
          const float* __restrict__ bhh1,
          const float* __restrict__ Wfc,   // [C][H]
          const float* __restrict__ bfc,   // [C]
          float* __restrict__ out)         // [B][C]
{
    // ht layout: physical_byte(c, within_row_byte) = c*RB + (wrb ^ ((c&7)<<4))
    __shared__ __align__(16) _Float16 ht0[2][16 * (RB / 2)];
    __shared__ __align__(16) _Float16 ht1[2][16 * (RB / 2)];
    __shared__ float xs[16 * XS];
    __shared__ __align__(16) float bias_lds[3 * Hh];  // [0]=b0sum [1]=b1sum [2]=wi0

    const int tid  = threadIdx.x;
    const int lane = tid & 63;
    const int w    = tid >> 6;     // wave 0..7 -> features [32w, 32w+32)
    const int q    = lane >> 4;
    const int c    = lane & 15;    // batch col within block
    const int bb   = blockIdx.x * 16;
    const int d    = c & 7;

    // ---- one-time: stage weight A-fragments (f16) ----
    // wi1, wh1 -> AGPR half (pinned, 128 exactly). wh0 -> arch VGPRs (64).
    f16x8 wh0[2][8], wi1[2][8], wh1[2][8];
#pragma unroll
    for (int mt = 0; mt < 2; ++mt) {
        const int fb = 32 * w + 16 * mt;
        const int m = fb + c;
#pragma unroll
        for (int kt = 0; kt < 8; ++kt) {
            const int off = m * Hh + kt * 32 + q * 8;
            {
                const float4 a0 = *(const float4*)(Whh0 + off);
                const float4 a1 = *(const float4*)(Whh0 + off + 4);
                wh0[mt][kt] = (f16x8){(_Float16)a0.x, (_Float16)a0.y, (_Float16)a0.z, (_Float16)a0.w,
                                      (_Float16)a1.x, (_Float16)a1.y, (_Float16)a1.z, (_Float16)a1.w};
            }
            {
                const float4 a0 = *(const float4*)(Wih1 + off);
                const float4 a1 = *(const float4*)(Wih1 + off + 4);
                wi1[mt][kt] = (f16x8){(_Float16)a0.x, (_Float16)a0.y, (_Float16)a0.z, (_Float16)a0.w,
                                      (_Float16)a1.x, (_Float16)a1.y, (_Float16)a1.z, (_Float16)a1.w};
                PIN_AGPR(wi1[mt][kt]);
            }
            {
                const float4 a0 = *(const float4*)(Whh1 + off);
                const float4 a1 = *(const float4*)(Whh1 + off + 4);
                wh1[mt][kt] = (f16x8){(_Float16)a0.x, (_Float16)a0.y, (_Float16)a0.z, (_Float16)a0.w,
                                      (_Float16)a1.x, (_Float16)a1.y, (_Float16)a1.z, (_Float16)a1.w};
                PIN_AGPR(wh1[mt][kt]);
            }
        }
    }

    // ---- init LDS: x tile, biases, ht1 = 0 (both buffers), ht0[0] ----
    for (int i = tid; i < 16 * Tt; i += 512) {
        const int b = i / Tt, t = i - b * Tt;
        xs[b * XS + t] = x[(bb + b) * Tt + t];
    }
    if (tid < Hh) {
        bias_lds[tid]           = bih0[tid] + bhh0[tid];
        bias_lds[Hh + tid]      = bih1[tid] + bhh1[tid];
        bias_lds[2 * Hh + tid]  = Wih0[tid];
    }
    {
        _Float16* z = &ht1[0][0];
        for (int i = tid; i < 2 * 16 * (RB / 2); i += 512) z[i] = (_Float16)0.f;
    }
    for (int i = tid; i < 16 * Hh; i += 512) {
        const int b = i >> 8, f = i & 255;
        const float xv0 = x[(bb + b) * Tt];
        // swizzled scalar f16 write: row b, within-row byte (2f) ^ ((b&7)<<4)
        char* p = (char*)&ht0[0][0] + b * RB + ((2 * f) ^ ((b & 7) << 4));
        *(_Float16*)p = (_Float16)tanh_fast(xv0 * Wih0[f] + bih0[f] + bhh0[f]);
    }
    __syncthreads();

    // Swizzled B-read base: lane (q,c) kt reads logical within-row bytes
    // [64kt+16q, +16). Physical = (64kt+16q) ^ (16d). Folds to:
    //   rbase = c*RB + 16*(q ^ (d&3)) + 64*(d>>2)
    //   off(kt) = (rbase ^ ((kt&1)<<6)) + 128*(kt>>1)
    const int rbase = c * RB + 16 * (q ^ (d & 3)) + 64 * (d >> 2);
    // Swizzled D-write base: logical byte 64w+32mt+8q -> physical
    //   wbase ^ (mt<<5), wbase = c*RB + ((64w+8q) ^ (16d))
    const int wbase = c * RB + ((64 * w + 8 * q) ^ (16 * d));
    const int fq    = 32 * w + 4 * q;            // bias base for mt=0 (+16 for mt=1)

#define HT_RD(base, kt) (*(const f16x8*)((const char*)(base) + ((rbase ^ (((kt) & 1) << 6)) + (((kt) >> 1) << 7))))

    // ---- main recurrence, time-skewed (R16 phase order):
    // step s: B0 = ht0[s]; produce ht0[s+1] (Whh0) and ht1[s] (Wih1 + Whh1)
#pragma unroll 1
    for (int s = 0; s < Tt; ++s) {
        const int cur = s & 1, nxt = cur ^ 1;
        const char* B0p = (const char*)&ht0[cur][0];
        const char* B1p = (const char*)&ht1[nxt][0];   // ht1[s-1]
        int sn = s + 1; if (sn >= Tt) sn = Tt - 1;  // last h0_next unused
        const float xv = xs[c * XS + sn];

        const f32x4 z4 = (f32x4){0.f, 0.f, 0.f, 0.f};

        // -- l0 MFMA: ai = Wih1 . ht0 ; ah0 = Whh0 . ht0 (shared B-frag)
        f32x4 ai[2]  = {z4, z4};
        f32x4 ah0[2] = {z4, z4};
#pragma unroll
        for (int kt = 0; kt < 8; ++kt) {
            const f16x8 B = HT_RD(B0p, kt);
            ai[0]  = __builtin_amdgcn_mfma_f32_16x16x32_f16(wi1[0][kt], B, ai[0],  0, 0, 0);
            ai[1]  = __builtin_amdgcn_mfma_f32_16x16x32_f16(wi1[1][kt], B, ai[1],  0, 0, 0);
            ah0[0] = __builtin_amdgcn_mfma_f32_16x16x32_f16(wh0[0][kt], B, ah0[0], 0, 0, 0);
            ah0[1] = __builtin_amdgcn_mfma_f32_16x16x32_f16(wh0[1][kt], B, ah0[1], 0, 0, 0);
        }

        // -- l0 finish: ht0[s+1] = tanh(ah0 + b0 + x_{s+1}*wi0); ah0 dies
#pragma unroll
        for (int mt = 0; mt < 2; ++mt) {
            const float4 b0r = *(const float4*)&bias_lds[fq + 16 * mt];
            const float4 w0r = *(const float4*)&bias_lds[2 * Hh + fq + 16 * mt];
            const float t0 = tanh_fast(ah0[mt][0] + b0r.x + xv * w0r.x);
            const float t1 = tanh_fast(ah0[mt][1] + b0r.y + xv * w0r.y);
            const float t2 = tanh_fast(ah0[mt][2] + b0r.z + xv * w0r.z);
            const float t3 = tanh_fast(ah0[mt][3] + b0r.w + xv * w0r.w);
            *(uint2*)((char*)&ht0[nxt][0] + (wbase ^ (mt << 5))) =
                make_uint2(pk2(t0, t1), pk2(t2, t3));
        }

        // -- l1 MFMA: ah1 = Whh1 . ht1[s-1] (independent chain, R16 style)
        f32x4 ah1[2] = {z4, z4};
#pragma unroll
        for (int kt = 0; kt < 8; ++kt) {
            const f16x8 B = HT_RD(B1p, kt);
            ah1[0] = __builtin_amdgcn_mfma_f32_16x16x32_f16(wh1[0][kt], B, ah1[0], 0, 0, 0);
            ah1[1] = __builtin_amdgcn_mfma_f32_16x16x32_f16(wh1[1][kt], B, ah1[1], 0, 0, 0);
        }

        // -- l1 finish: ht1[s] = tanh(ai + ah1 + b1)
#pragma unroll
        for (int mt = 0; mt < 2; ++mt) {
            const float4 b1r = *(const float4*)&bias_lds[Hh + fq + 16 * mt];
            const float t0 = tanh_fast(ai[mt][0] + ah1[mt][0] + b1r.x);
            const float t1 = tanh_fast(ai[mt][1] + ah1[mt][1] + b1r.y);
            const float t2 = tanh_fast(ai[mt][2] + ah1[mt][2] + b1r.z);
            const float t3 = tanh_fast(ai[mt][3] + ah1[mt][3] + b1r.w);
            *(uint2*)((char*)&ht1[cur][0] + (wbase ^ (mt << 5))) =
                make_uint2(pk2(t0, t1), pk2(t2, t3));
        }
        __syncthreads();   // double-buffered: one barrier per step
    }

    // ---- FC epilogue: out[bb+b][cls] = ht1_final[.][b] . Wfc[cls] + bfc ----
    if (tid < 16 * Cc) {
        const int b = tid / Cc, cls = tid - Cc * (tid / Cc);
        const char* hrow = (const char*)&ht1[(Tt - 1) & 1][0] + b * RB;
        const int bd = (b & 7) << 4;
        float acc = bfc[cls];
        for (int k = 0; k < Hh; ++k) {
            const _Float16 hv = *(const _Float16*)(hrow + ((2 * k) ^ bd));
            acc += (float)hv * Wfc[cls * Hh + k];
        }
        out[(bb + b) * Cc + cls] = acc;
    }
}

extern "C" void kernel_launch(void* const* d_in, const int* in_sizes, int n_in,
                              void* d_out, int out_size, void* d_ws, size_t ws_size,
                              hipStream_t stream) {
    rnn_fused<<<dim3(Bsz / 16), dim3(512), 0, stream>>>(
        (const float*)d_in[0],  // x
        (const float*)d_in[1],  // W_ih0
        (const float*)d_in[2],  // W_hh0
        (const float*)d_in[3],  // b_ih0
        (const float*)d_in[4],  // b_hh0
        (const float*)d_in[5],  // W_ih1
        (const float*)d_in[6],  // W_hh1
        (const float*)d_in[7],  // b_ih1
        (const float*)d_in[8],  // b_hh1
        (const float*)d_in[9],  // W_fc
        (const float*)d_in[10], // b_fc
        (float*)d_out);
}